// Round 2
// baseline (406.737 us; speedup 1.0000x reference)
//
#include <hip/hip_runtime.h>
#include <hip/hip_bf16.h>

// Problem: N=8, L=4096, H_in=512, H=512, 3H=1536.
// pre = x @ W^T + b  (M=32768 rows, 1536 cols, K=512), gate math in log space,
// then associative log-space scan over L per (n,h), out = exp(log_h).
//
// Input dtype (fp32 vs bf16) is detected at runtime on-device (see detect_dtype)
// and inputs are normalized to bf16 (x, W) / f32 (b) in workspace.

#define H_DIM 512
#define LSEQ 4096
#define NBATCH 8
#define M_TOTAL (NBATCH * LSEQ)  // 32768

// GEMM tiling
#define BM 128
#define BN 64            // per-gate columns per block (x3 gates = 192 acc cols)
#define BK 64
#define LDSS 72          // padded LDS row stride in shorts

// Scan chunking
#define CS 128
#define NC 32            // LSEQ / CS

typedef __attribute__((ext_vector_type(8))) short short8;
typedef __attribute__((ext_vector_type(4))) float floatx4;

#define NEG_BIG (-1.0e30f)

__device__ __forceinline__ float softplus_f(float z) {
    return fmaxf(z, 0.0f) + __logf(1.0f + __expf(-fabsf(z)));
}

__device__ __forceinline__ float logaddexp_f(float p, float q) {
    // finite-only (we use -1e30 sentinel instead of -inf) -> no NaN possible
    float m = fmaxf(p, q);
    float d = -fabsf(p - q);
    return m + __logf(1.0f + __expf(d));
}

__device__ __forceinline__ float bf16u_to_f(unsigned short u) {
    unsigned int w = ((unsigned int)u) << 16;
    float f;
    __builtin_memcpy(&f, &w, 4);
    return f;
}

__device__ __forceinline__ unsigned short f_to_bf16u(float f) {
    __hip_bfloat16 h = __float2bfloat16(f);
    unsigned short u;
    __builtin_memcpy(&u, &h, 2);
    return u;
}

// ---------------------------------------------------------------------------
// Kernel 0: dtype detector. Reads first 65536 u16 halves of x. If x is fp32,
// low halves of words are uniform mantissa bits -> ~128 bf16-NaN patterns.
// Genuine bf16 N(0,1) data -> 0. flag=1 means fp32 inputs.
// ---------------------------------------------------------------------------
__global__ void detect_dtype(const unsigned short* __restrict__ xu, int* flag) {
    __shared__ int cnt;
    if (threadIdx.x == 0) cnt = 0;
    __syncthreads();
    int local = 0;
    for (int i = threadIdx.x; i < 65536; i += 256) {
        unsigned short u = xu[i];
        if (((u >> 7) & 0xFF) == 0xFF) local++;
    }
    if (local) atomicAdd(&cnt, local);
    __syncthreads();
    if (threadIdx.x == 0) flag[0] = (cnt > 8) ? 1 : 0;
}

// ---------------------------------------------------------------------------
// Kernel 0b: normalize an input array to bf16 (copy-through if already bf16).
// n must be divisible by 8.
// ---------------------------------------------------------------------------
__global__ void convert_bf16(const void* __restrict__ src,
                             unsigned short* __restrict__ dst,
                             int n, const int* __restrict__ flag) {
    int i = (blockIdx.x * blockDim.x + threadIdx.x) * 8;
    if (i >= n) return;
    if (*flag) {
        const float* s = (const float*)src;
        short8 v;
        #pragma unroll
        for (int j = 0; j < 8; j++) v[j] = (short)f_to_bf16u(s[i + j]);
        *(short8*)&dst[i] = v;
    } else {
        *(short8*)&dst[i] = *(const short8*)&((const short*)src)[i];
    }
}

// Kernel 0c: bias -> f32
__global__ void convert_bias(const void* __restrict__ src,
                             float* __restrict__ dst,
                             const int* __restrict__ flag) {
    int i = blockIdx.x * blockDim.x + threadIdx.x;
    if (i >= 3 * H_DIM) return;
    if (*flag) dst[i] = ((const float*)src)[i];
    else       dst[i] = bf16u_to_f(((const unsigned short*)src)[i]);
}

// ---------------------------------------------------------------------------
// Kernel 1: GEMM + fused gate math.
// Block: 256 threads (4 waves). Tile: 128 rows x (3 gates x 64 cols).
// ---------------------------------------------------------------------------
__global__ __launch_bounds__(256, 2)
void gemm_gates(const unsigned short* __restrict__ x,
                const unsigned short* __restrict__ W,
                const float* __restrict__ bias,
                float* __restrict__ lf_out,
                float* __restrict__ lv_out) {
    __shared__ short Alds[BM * LDSS];
    __shared__ short Blds[192 * LDSS];

    const int bx = blockIdx.x;               // col block 0..7
    const int by = blockIdx.y;               // row block 0..255
    const int tid = threadIdx.x;
    const int lane = tid & 63;
    const int w = tid >> 6;

    const int R0 = by * BM;

    floatx4 acc[2][12];
    #pragma unroll
    for (int i = 0; i < 2; i++)
        #pragma unroll
        for (int j = 0; j < 12; j++)
            acc[i][j] = (floatx4){0.f, 0.f, 0.f, 0.f};

    const short* xg = (const short*)x;
    const short* wg = (const short*)W;

    for (int k0 = 0; k0 < H_DIM; k0 += BK) {
        __syncthreads();
        #pragma unroll
        for (int i = 0; i < 4; i++) {
            int v = tid + 256 * i;
            int row = v >> 3, seg = v & 7;
            short8 val = *(const short8*)&xg[(size_t)(R0 + row) * H_DIM + k0 + seg * 8];
            *(short8*)&Alds[row * LDSS + seg * 8] = val;
        }
        #pragma unroll
        for (int i = 0; i < 6; i++) {
            int v = tid + 256 * i;
            int c = v >> 3, seg = v & 7;
            int o = (c >> 6) * H_DIM + bx * BN + (c & 63);
            short8 val = *(const short8*)&wg[(size_t)o * H_DIM + k0 + seg * 8];
            *(short8*)&Blds[c * LDSS + seg * 8] = val;
        }
        __syncthreads();

        #pragma unroll
        for (int ks = 0; ks < 2; ks++) {
            const int kk = ks * 32 + (lane >> 4) * 8;
            short8 afrag[2];
            #pragma unroll
            for (int mt = 0; mt < 2; mt++)
                afrag[mt] = *(const short8*)&Alds[(w * 32 + mt * 16 + (lane & 15)) * LDSS + kk];
            #pragma unroll
            for (int nt = 0; nt < 12; nt++) {
                short8 bfrag = *(const short8*)&Blds[(nt * 16 + (lane & 15)) * LDSS + kk];
                acc[0][nt] = __builtin_amdgcn_mfma_f32_16x16x32_bf16(afrag[0], bfrag, acc[0][nt], 0, 0, 0);
                acc[1][nt] = __builtin_amdgcn_mfma_f32_16x16x32_bf16(afrag[1], bfrag, acc[1][nt], 0, 0, 0);
            }
        }
    }

    // Epilogue: C/D layout col=lane&15, row=(lane>>4)*4+reg [m89/m91]
    const int colbase = bx * BN + (lane & 15);
    const int rowbase = R0 + w * 32 + ((lane >> 4) << 2);
    #pragma unroll
    for (int jj = 0; jj < 4; jj++) {
        int hcol = colbase + jj * 16;
        float bf = bias[hcol];
        float bi = bias[H_DIM + hcol];
        float bh = bias[2 * H_DIM + hcol];
        #pragma unroll
        for (int mt = 0; mt < 2; mt++) {
            #pragma unroll
            for (int r = 0; r < 4; r++) {
                float fp = acc[mt][jj][r] + bf;
                float ip = acc[mt][4 + jj][r] + bi;
                float hp = acc[mt][8 + jj][r] + bh;
                float diff = softplus_f(-fp) - softplus_f(-ip);
                float lf = -softplus_f(diff);            // log f'
                float li = -softplus_f(-diff);           // log i'
                float lg = (hp >= 0.f) ? __logf(hp + 0.5f) : -softplus_f(-hp);
                int row = rowbase + mt * 16 + r;
                size_t idx = (size_t)row * H_DIM + hcol;
                lf_out[idx] = lf;
                lv_out[idx] = li + lg;
            }
        }
    }
}

// ---------------------------------------------------------------------------
// Kernel 2: per-chunk summary. A_c = sum(log_f), B_c = chunk-local scan
// ---------------------------------------------------------------------------
__global__ __launch_bounds__(256)
void scan_chunks(const float* __restrict__ lf, const float* __restrict__ lv,
                 float* __restrict__ Asum, float* __restrict__ Bval) {
    int h = blockIdx.x * 256 + threadIdx.x;
    int c = blockIdx.y;
    int n = blockIdx.z;
    size_t base = ((size_t)n * LSEQ + (size_t)c * CS) * H_DIM + h;
    float a = 0.f;
    float bacc = NEG_BIG;
    for (int t = 0; t < CS; t++) {
        float f = lf[base + (size_t)t * H_DIM];
        float v = lv[base + (size_t)t * H_DIM];
        bacc = logaddexp_f(f + bacc, v);
        a += f;
    }
    size_t o = ((size_t)n * NC + c) * H_DIM + h;
    Asum[o] = a;
    Bval[o] = bacc;
}

// ---------------------------------------------------------------------------
// Kernel 3: sequential combine of chunk summaries -> carry-in per chunk
// ---------------------------------------------------------------------------
__global__ __launch_bounds__(512)
void scan_carries(const float* __restrict__ Asum, const float* __restrict__ Bval,
                  float* __restrict__ carryin) {
    int n = blockIdx.x;
    int h = threadIdx.x;
    float carry = -13.815510558f;  // log(1e-6)
    for (int c = 0; c < NC; c++) {
        size_t o = ((size_t)n * NC + c) * H_DIM + h;
        carryin[o] = carry;
        carry = logaddexp_f(Asum[o] + carry, Bval[o]);
    }
}

// ---------------------------------------------------------------------------
// Kernel 4: replay chunks with carry, write exp(log_h) (dtype per flag)
// ---------------------------------------------------------------------------
__global__ __launch_bounds__(256)
void scan_apply(const float* __restrict__ lf, const float* __restrict__ lv,
                const float* __restrict__ carryin,
                void* __restrict__ outv, const int* __restrict__ flag) {
    int h = blockIdx.x * 256 + threadIdx.x;
    int c = blockIdx.y;
    int n = blockIdx.z;
    const int f32out = *flag;
    float r = carryin[((size_t)n * NC + c) * H_DIM + h];
    size_t base = ((size_t)n * LSEQ + (size_t)c * CS) * H_DIM + h;
    float* of = (float*)outv;
    __hip_bfloat16* ob = (__hip_bfloat16*)outv;
    for (int t = 0; t < CS; t++) {
        float f = lf[base + (size_t)t * H_DIM];
        float v = lv[base + (size_t)t * H_DIM];
        r = logaddexp_f(f + r, v);
        float hval = __expf(r);
        size_t idx = base + (size_t)t * H_DIM;
        if (f32out) of[idx] = hval;
        else        ob[idx] = __float2bfloat16(hval);
    }
}

extern "C" void kernel_launch(void* const* d_in, const int* in_sizes, int n_in,
                              void* d_out, int out_size, void* d_ws, size_t ws_size,
                              hipStream_t stream) {
    const void* x = d_in[0];
    const void* W = d_in[1];
    const void* b = d_in[2];

    // workspace layout (bytes):
    char* wsb = (char*)d_ws;
    int* flag            = (int*)wsb;                          // 16 B
    float* bconv         = (float*)(wsb + 16);                 // 6 KB
    unsigned short* xc   = (unsigned short*)(wsb + 16384);     // 32 MB
    unsigned short* Wc   = (unsigned short*)(wsb + 16384 + 33554432);
    float* lf            = (float*)(wsb + 35143680);           // 64 MB
    float* lv            = (float*)(wsb + 102252544);          // 64 MB
    float* Asum          = (float*)(wsb + 169361408);          // 512 KB
    float* Bval          = Asum + (size_t)NBATCH * NC * H_DIM;
    float* cin           = Bval + (size_t)NBATCH * NC * H_DIM;

    const int NX = M_TOTAL * H_DIM;        // 16777216
    const int NW = 3 * H_DIM * H_DIM;      // 786432

    detect_dtype<<<1, 256, 0, stream>>>((const unsigned short*)x, flag);
    convert_bf16<<<(NX / 8 + 255) / 256, 256, 0, stream>>>(x, xc, NX, flag);
    convert_bf16<<<(NW / 8 + 255) / 256, 256, 0, stream>>>(W, Wc, NW, flag);
    convert_bias<<<6, 256, 0, stream>>>(b, bconv, flag);

    dim3 g1(H_DIM / BN, M_TOTAL / BM);   // (8, 256)
    gemm_gates<<<g1, 256, 0, stream>>>(xc, Wc, bconv, lf, lv);

    dim3 g2(H_DIM / 256, NC, NBATCH);    // (2, 32, 8)
    scan_chunks<<<g2, 256, 0, stream>>>(lf, lv, Asum, Bval);
    scan_carries<<<NBATCH, H_DIM, 0, stream>>>(Asum, Bval, cin);
    scan_apply<<<g2, 256, 0, stream>>>(lf, lv, cin, d_out, flag);
}

// Round 3
// 295.734 us; speedup vs baseline: 1.3753x; 1.3753x over previous
//
#include <hip/hip_runtime.h>
#include <hip/hip_bf16.h>

// minLSTM: pre = x @ W^T + b (M=32768, N=1536, K=512), log-space gates,
// chunked log-space scan over L=4096 per (n,h), out = exp(log_h).
// Inputs detected fp32-vs-bf16 on device; normalized to bf16 for MFMA.

#define H_DIM 512
#define LSEQ 4096
#define NBATCH 8
#define M_TOTAL (NBATCH * LSEQ)  // 32768

// GEMM tiling: block = 128 rows x (3 gates x 64 cols) = 128 x 192, BK=64
#define BM 128
#define BK 64

// Scan chunking
#define CS 128
#define NC 32            // LSEQ / CS

typedef __attribute__((ext_vector_type(8))) short short8;
typedef __attribute__((ext_vector_type(4))) float floatx4;
typedef _Float16 h2 __attribute__((ext_vector_type(2)));

#define NEG_BIG (-1.0e30f)

__device__ __forceinline__ float softplus_f(float z) {
    return fmaxf(z, 0.0f) + __logf(1.0f + __expf(-fabsf(z)));
}

__device__ __forceinline__ float logaddexp_f(float p, float q) {
    float m = fmaxf(p, q);
    float d = -fabsf(p - q);
    return m + __logf(1.0f + __expf(d));
}

__device__ __forceinline__ float bf16u_to_f(unsigned short u) {
    unsigned int w = ((unsigned int)u) << 16;
    float f;
    __builtin_memcpy(&f, &w, 4);
    return f;
}

__device__ __forceinline__ unsigned short f_to_bf16u(float f) {
    __hip_bfloat16 h = __float2bfloat16(f);
    unsigned short u;
    __builtin_memcpy(&u, &h, 2);
    return u;
}

// async global(16B/lane) -> LDS (wave-uniform base + lane*16)
__device__ __forceinline__ void gload_lds16(const void* g, void* l) {
    __builtin_amdgcn_global_load_lds(
        (const __attribute__((address_space(1))) unsigned int*)g,
        (__attribute__((address_space(3))) unsigned int*)l, 16, 0, 0);
}

// ---------------------------------------------------------------------------
// Kernel 0: dtype detect (fp32 vs bf16) + bias -> f32. Single block.
// fp32 data: low 16-bit halves are uniform -> bf16-NaN pattern P=1/256,
// E[hits in 8192 low halves] = 32. bf16 N(0,1) data: 0 hits.
// ---------------------------------------------------------------------------
__global__ void detect_and_bias(const unsigned short* __restrict__ xu,
                                const void* __restrict__ bsrc,
                                int* __restrict__ flag,
                                float* __restrict__ bdst) {
    __shared__ int cnt;
    if (threadIdx.x == 0) cnt = 0;
    __syncthreads();
    int local = 0;
    for (int i = threadIdx.x; i < 16384; i += 256) {
        unsigned short u = xu[i];
        if (((u >> 7) & 0xFF) == 0xFF) local++;
    }
    if (local) atomicAdd(&cnt, local);
    __syncthreads();
    int f = (cnt > 4) ? 1 : 0;
    if (threadIdx.x == 0) flag[0] = f;
    for (int i = threadIdx.x; i < 3 * H_DIM; i += 256) {
        bdst[i] = f ? ((const float*)bsrc)[i]
                    : bf16u_to_f(((const unsigned short*)bsrc)[i]);
    }
}

// ---------------------------------------------------------------------------
// Kernel 0b: normalize an input array to bf16 (copy-through if already bf16)
// ---------------------------------------------------------------------------
__global__ void convert_bf16(const void* __restrict__ src,
                             unsigned short* __restrict__ dst,
                             int n, const int* __restrict__ flag) {
    int i = (blockIdx.x * blockDim.x + threadIdx.x) * 8;
    if (i >= n) return;
    if (*flag) {
        const float* s = (const float*)src;
        short8 v;
        #pragma unroll
        for (int j = 0; j < 8; j++) v[j] = (short)f_to_bf16u(s[i + j]);
        *(short8*)&dst[i] = v;
    } else {
        *(short8*)&dst[i] = *(const short8*)&((const short*)src)[i];
    }
}

// ---------------------------------------------------------------------------
// Kernel 1: GEMM + fused gate math (m97 structure).
// Block 256 = 4 waves in 2x2: wave (wr, wc2) covers rows wr..wr+63,
// nt tiles {g*4 + wc2*2 + jj : g gates, jj 0..1} (so f/i/h cols lane-local).
// global_load_lds width-16 staging, unpadded LDS.
// Output: packed (lf, lv) as f16x2 per element.
// ---------------------------------------------------------------------------
__global__ __launch_bounds__(256, 2)
void gemm_gates(const unsigned short* __restrict__ x,
                const unsigned short* __restrict__ W,
                const float* __restrict__ bias,
                h2* __restrict__ plv) {
    __shared__ short Alds[BM * BK];        // 16 KB, [row][64k] unpadded
    __shared__ short Blds[192 * BK];       // 24 KB

    const int bx = blockIdx.x;             // col block 0..7 (64 cols/gate)
    const int by = blockIdx.y;             // row block 0..255
    const int tid = threadIdx.x;
    const int lane = tid & 63;
    const int w = tid >> 6;
    const int wr = (w >> 1) * 64;          // wave row offset
    const int wc2 = w & 1;                 // wave col group
    const int l8 = lane >> 3, s8 = lane & 7;
    const int fr = lane & 15;              // fragment row
    const int q = lane >> 4;               // quad

    const int R0 = by * BM;

    floatx4 acc[4][6];
    #pragma unroll
    for (int i = 0; i < 4; i++)
        #pragma unroll
        for (int j = 0; j < 6; j++)
            acc[i][j] = (floatx4){0.f, 0.f, 0.f, 0.f};

    const short* xg = (const short*)x;
    const short* wg = (const short*)W;

    for (int k0 = 0; k0 < H_DIM; k0 += BK) {
        __syncthreads();
        // A: 16 chunks of 8 rows x 64k (1 KB each); wave w stages 4
        #pragma unroll
        for (int i = 0; i < 4; i++) {
            int c = w * 4 + i;
            const short* g = xg + (size_t)(R0 + c * 8 + l8) * H_DIM + k0 + s8 * 8;
            gload_lds16(g, &Alds[c * 512]);
        }
        // B: 24 chunks of 8 rows; B-row br -> W row (br>>6)*512 + bx*64 + (br&63)
        #pragma unroll
        for (int i = 0; i < 6; i++) {
            int c = w * 6 + i;
            int br = c * 8 + l8;
            int wrow = (br >> 6) * H_DIM + bx * 64 + (br & 63);
            const short* g = wg + (size_t)wrow * H_DIM + k0 + s8 * 8;
            gload_lds16(g, &Blds[c * 512]);
        }
        __syncthreads();

        #pragma unroll
        for (int ks = 0; ks < 2; ks++) {
            const int kk = ks * 32 + q * 8;
            short8 af[4], bf[6];
            #pragma unroll
            for (int mt = 0; mt < 4; mt++)
                af[mt] = *(const short8*)&Alds[(wr + mt * 16 + fr) * BK + kk];
            #pragma unroll
            for (int j = 0; j < 6; j++) {
                int nt = (j >> 1) * 4 + wc2 * 2 + (j & 1);
                bf[j] = *(const short8*)&Blds[(nt * 16 + fr) * BK + kk];
            }
            #pragma unroll
            for (int mt = 0; mt < 4; mt++)
                #pragma unroll
                for (int j = 0; j < 6; j++)
                    acc[mt][j] = __builtin_amdgcn_mfma_f32_16x16x32_bf16(
                        af[mt], bf[j], acc[mt][j], 0, 0, 0);
        }
    }

    // Epilogue: C/D layout col=lane&15, row=quad*4+reg [m89/m91].
    // acc[mt][g*2+jj] is gate g, within-gate col = bx*64 + wc2*32 + jj*16 + fr
    const int rowb = R0 + wr + q * 4;
    #pragma unroll
    for (int jj = 0; jj < 2; jj++) {
        int hcol = bx * 64 + wc2 * 32 + jj * 16 + fr;
        float bfv = bias[hcol];
        float biv = bias[H_DIM + hcol];
        float bhv = bias[2 * H_DIM + hcol];
        #pragma unroll
        for (int mt = 0; mt < 4; mt++) {
            #pragma unroll
            for (int r = 0; r < 4; r++) {
                float fp = acc[mt][jj][r] + bfv;
                float ip = acc[mt][2 + jj][r] + biv;
                float hp = acc[mt][4 + jj][r] + bhv;
                float diff = softplus_f(-fp) - softplus_f(-ip);
                float lf = -softplus_f(diff);            // log f'
                float li = -softplus_f(-diff);           // log i'
                float lg = (hp >= 0.f) ? __logf(hp + 0.5f) : -softplus_f(-hp);
                float lv = li + lg;
                int row = rowb + mt * 16 + r;
                h2 pk;
                pk[0] = (_Float16)lf;
                pk[1] = (_Float16)lv;
                plv[(size_t)row * H_DIM + hcol] = pk;
            }
        }
    }
}

// ---------------------------------------------------------------------------
// Kernel 2: per-chunk summary. A_c = sum(log_f), B_c = chunk-local scan
// ---------------------------------------------------------------------------
__global__ __launch_bounds__(256)
void scan_chunks(const h2* __restrict__ plv,
                 float* __restrict__ Asum, float* __restrict__ Bval) {
    int h = blockIdx.x * 256 + threadIdx.x;
    int c = blockIdx.y;
    int n = blockIdx.z;
    size_t base = ((size_t)n * LSEQ + (size_t)c * CS) * H_DIM + h;
    float a = 0.f;
    float bacc = NEG_BIG;
    for (int t = 0; t < CS; t++) {
        h2 p = plv[base + (size_t)t * H_DIM];
        float f = (float)p[0];
        float v = (float)p[1];
        bacc = logaddexp_f(f + bacc, v);
        a += f;
    }
    size_t o = ((size_t)n * NC + c) * H_DIM + h;
    Asum[o] = a;
    Bval[o] = bacc;
}

// ---------------------------------------------------------------------------
// Kernel 3: sequential combine of chunk summaries -> carry-in per chunk
// ---------------------------------------------------------------------------
__global__ __launch_bounds__(512)
void scan_carries(const float* __restrict__ Asum, const float* __restrict__ Bval,
                  float* __restrict__ carryin) {
    int n = blockIdx.x;
    int h = threadIdx.x;
    float carry = -13.815510558f;  // log(1e-6)
    for (int c = 0; c < NC; c++) {
        size_t o = ((size_t)n * NC + c) * H_DIM + h;
        carryin[o] = carry;
        carry = logaddexp_f(Asum[o] + carry, Bval[o]);
    }
}

// ---------------------------------------------------------------------------
// Kernel 4: replay chunks with carry, write exp(log_h) (dtype per flag)
// ---------------------------------------------------------------------------
__global__ __launch_bounds__(256)
void scan_apply(const h2* __restrict__ plv,
                const float* __restrict__ carryin,
                void* __restrict__ outv, const int* __restrict__ flag) {
    int h = blockIdx.x * 256 + threadIdx.x;
    int c = blockIdx.y;
    int n = blockIdx.z;
    const int f32out = *flag;
    float r = carryin[((size_t)n * NC + c) * H_DIM + h];
    size_t base = ((size_t)n * LSEQ + (size_t)c * CS) * H_DIM + h;
    float* of = (float*)outv;
    __hip_bfloat16* ob = (__hip_bfloat16*)outv;
    for (int t = 0; t < CS; t++) {
        h2 p = plv[base + (size_t)t * H_DIM];
        r = logaddexp_f((float)p[0] + r, (float)p[1]);
        float hval = __expf(r);
        size_t idx = base + (size_t)t * H_DIM;
        if (f32out) of[idx] = hval;
        else        ob[idx] = __float2bfloat16(hval);
    }
}

extern "C" void kernel_launch(void* const* d_in, const int* in_sizes, int n_in,
                              void* d_out, int out_size, void* d_ws, size_t ws_size,
                              hipStream_t stream) {
    const void* x = d_in[0];
    const void* W = d_in[1];
    const void* b = d_in[2];

    char* wsb = (char*)d_ws;
    int* flag            = (int*)wsb;                          // 16 B
    float* bconv         = (float*)(wsb + 16);                 // 6 KB
    unsigned short* xc   = (unsigned short*)(wsb + 16384);     // 32 MB
    unsigned short* Wc   = (unsigned short*)(wsb + 16384 + 33554432);  // 1.5 MB
    h2* plv              = (h2*)(wsb + 36700160);              // 64 MB packed (lf,lv)
    float* Asum          = (float*)(wsb + 36700160 + 67108864);// 512 KB
    float* Bval          = Asum + (size_t)NBATCH * NC * H_DIM;
    float* cin           = Bval + (size_t)NBATCH * NC * H_DIM;

    const int NX = M_TOTAL * H_DIM;        // 16777216
    const int NW = 3 * H_DIM * H_DIM;      // 786432

    detect_and_bias<<<1, 256, 0, stream>>>((const unsigned short*)x, b, flag, bconv);
    convert_bf16<<<(NX / 8 + 255) / 256, 256, 0, stream>>>(x, xc, NX, flag);
    convert_bf16<<<(NW / 8 + 255) / 256, 256, 0, stream>>>(W, Wc, NW, flag);

    dim3 g1(H_DIM / 64, M_TOTAL / BM);   // (8, 256)
    gemm_gates<<<g1, 256, 0, stream>>>(xc, Wc, bconv, plv);

    dim3 g2(H_DIM / 256, NC, NBATCH);    // (2, 32, 8)
    scan_chunks<<<g2, 256, 0, stream>>>(plv, Asum, Bval);
    scan_carries<<<NBATCH, H_DIM, 0, stream>>>(Asum, Bval, cin);
    scan_apply<<<g2, 256, 0, stream>>>(plv, cin, d_out, flag);
}